// Round 1
// baseline (266.473 us; speedup 1.0000x reference)
//
#include <hip/hip_runtime.h>

#define NPTS 1600
#define NCHUNK 10
#define CHUNKJ 160
#define TILE 32
// scale*log2e folded into Q
#define QS (0.35355339059327373f*1.4426950408889634f)
// 1/(sqrt(2)*6)
#define PSCALE 0.11785113019775793f

__device__ __forceinline__ float leaky(float x){ return x >= 0.f ? x : 0.2f*x; }
__device__ __forceinline__ float d4(float4 a, float4 b){ return a.x*b.x + a.y*b.y + a.z*b.z + a.w*b.w; }

// ---------------- K1: h = leaky(leaky(f@w1+b1)@w2+b2); group stats; fold rbf into conv_w1 ----------------
__global__ __launch_bounds__(256) void k_in(
    const float* __restrict__ feat, const float* __restrict__ w1, const float* __restrict__ b1,
    const float* __restrict__ w2, const float* __restrict__ b2,
    const float* __restrict__ conv_w1, const float* __restrict__ conv_b1,
    const float* __restrict__ rbf_a, const float* __restrict__ rbf_b,
    float* __restrict__ h2out, float* __restrict__ stats,
    float* __restrict__ wrg, float* __restrict__ b1pg)
{
  __shared__ float sh[4][64];
  __shared__ float sred[4][8];
  int t = threadIdx.x, w = t>>6, c = t&63;
  int i = blockIdx.x*4 + w;

  if (blockIdx.x == 0) {
    if (t < 64) {
      int cc = t>>3, k = t&7; float s = 0.f;
      #pragma unroll
      for (int p=0;p<4;p++) s += conv_w1[cc*8+4+p]*rbf_a[p*8+k];
      wrg[t] = s;
    } else if (t < 72) {
      int cc = t-64; float s = conv_b1[cc];
      #pragma unroll
      for (int p=0;p<4;p++) s += conv_w1[cc*8+4+p]*rbf_b[p];
      b1pg[cc] = s;
    }
  }

  const float4* f4 = (const float4*)(feat + i*16);
  float4 f0=f4[0], f1v=f4[1], f2v=f4[2], f3v=f4[3];
  const float4* w1r = (const float4*)(w1 + c*16);
  float h1 = b1[c] + d4(f0,w1r[0]) + d4(f1v,w1r[1]) + d4(f2v,w1r[2]) + d4(f3v,w1r[3]);
  h1 = leaky(h1);
  sh[w][c] = h1;
  __syncthreads();
  float hh = b2[c];
  #pragma unroll
  for (int k4=0;k4<16;k4++){
    float4 hv = *(const float4*)&sh[w][k4*4];
    hh += d4(hv, *(const float4*)&w2[c*64 + k4*4]);
  }
  hh = leaky(hh);
  h2out[i*64+c] = hh;

  float s = hh, qq = hh*hh;
  s += __shfl_xor(s,1);  qq += __shfl_xor(qq,1);
  s += __shfl_xor(s,2);  qq += __shfl_xor(qq,2);
  s += __shfl_xor(s,4);  qq += __shfl_xor(qq,4);
  s += __shfl_xor(s,8);  qq += __shfl_xor(qq,8);
  if ((c&15)==0){ int g=c>>4; sred[w][g]=s; sred[w][4+g]=qq; }
  __syncthreads();
  if (t<8){ float v2 = sred[0][t]+sred[1][t]+sred[2][t]+sred[3][t]; atomicAdd(&stats[t], v2); }
}

// ---------------- K2: group-norm + Q/K/V projections (Q pre-scaled) ----------------
__global__ __launch_bounds__(256) void k_qkv(
  const float* __restrict__ h2, const float* __restrict__ stats,
  const float* __restrict__ g_in, const float* __restrict__ be_in,
  const float* __restrict__ wq, const float* __restrict__ bq,
  const float* __restrict__ wk, const float* __restrict__ bk,
  const float* __restrict__ wv, const float* __restrict__ bv,
  float* __restrict__ Q, float* __restrict__ K, float* __restrict__ V)
{
  __shared__ float sh[4][64];
  int t=threadIdx.x, w=t>>6, c=t&63;
  int i = blockIdx.x*4 + w;
  int g = c>>4;
  const float inv = 1.f/25600.f;
  float mu = stats[g]*inv;
  float var = stats[4+g]*inv - mu*mu;
  float rs = rsqrtf(var + 1e-5f);
  float hn = (h2[i*64+c]-mu)*rs*g_in[c] + be_in[c];
  sh[w][c] = hn;
  __syncthreads();
  float q=bq[c], k=bk[c], v=bv[c];
  #pragma unroll
  for (int k4=0;k4<16;k4++){
    float4 hv = *(const float4*)&sh[w][k4*4];
    q += d4(hv, *(const float4*)&wq[c*64+k4*4]);
    k += d4(hv, *(const float4*)&wk[c*64+k4*4]);
    v += d4(hv, *(const float4*)&wv[c*64+k4*4]);
  }
  Q[i*64+c] = q*QS;
  K[i*64+c] = k;
  V[i*64+c] = v;
}

// ---------------- K3: the all-pairs kernel ----------------
__global__ __launch_bounds__(256) void k_pair(
  const float* __restrict__ Qm, const float* __restrict__ Km, const float* __restrict__ Vm,
  const float* __restrict__ pts, const float* __restrict__ nuv,
  const float* __restrict__ w1, const float* __restrict__ wrg, const float* __restrict__ b1pg,
  const float* __restrict__ w2g, const float* __restrict__ b2g,
  const float* __restrict__ rbf_ls, const float* __restrict__ ceng,
  float* __restrict__ part)
{
  __shared__ __align__(16) float sQ[16][68];
  __shared__ __align__(16) float sWX[16][36];
  __shared__ __align__(16) float sKx[TILE][68];
  __shared__ __align__(16) float sVx[TILE][68];
  __shared__ __align__(16) float sPt[TILE][4];
  __shared__ __align__(16) float sNj[TILE][4];
  __shared__ __align__(16) float sRed[4][16][72];

  int t = threadIdx.x;
  int r = t & 15, jl = t >> 4;
  int bx = blockIdx.x;
  int rb = bx % 100, jc = bx / 100;
  int I0 = rb*16, J0 = jc*CHUNKJ;
  int i = I0 + r;

  { // stage Q rows (16x64 = 1024 floats, 1 float4/thread)
    int row = t >> 4, col = (t & 15) << 2;
    *(float4*)&sQ[row][col] = *(const float4*)&Qm[(I0+row)*64 + col];
  }
  if (t < 128) { // per-row folded Xloc weights: wx[c][b] = sum_a w1[c,a]*nuv[i,a,b]; wx[c][3]=w1[c,3]
    int r2 = t >> 3, cc = t & 7;
    int ib = (I0+r2)*9;
    #pragma unroll
    for (int b=0;b<3;b++)
      sWX[r2][cc*4+b] = w1[cc*8+0]*nuv[ib+b] + w1[cc*8+1]*nuv[ib+3+b] + w1[cc*8+2]*nuv[ib+6+b];
    sWX[r2][cc*4+3] = w1[cc*8+3];
  }

  float ls = rbf_ls[0];
  float sig = fmaxf(expf(ls), 1e-6f);
  float mexp = -1.4426950408889634f/(2.f*sig*sig); // exp2-domain
  float cen[8];
  #pragma unroll
  for (int k=0;k<8;k++) cen[k] = ceng[k];

  float pix = pts[i*3+0]*PSCALE, piy = pts[i*3+1]*PSCALE, piz = pts[i*3+2]*PSCALE;
  float nix = nuv[i*9+0], niy = nuv[i*9+1], niz = nuv[i*9+2];

  float acc[64];
  #pragma unroll
  for (int o=0;o<64;o++) acc[o] = 0.f;
  float lh[8];
  #pragma unroll
  for (int h=0;h<8;h++) lh[h] = 0.f;

  #pragma unroll 1
  for (int tb=0; tb<CHUNKJ; tb+=TILE) {
    int jbase = J0 + tb;
    __syncthreads();
    #pragma unroll
    for (int qq2=0; qq2<2; qq2++) { // stage K,V tile: 2x2048 floats
      int idx4 = t + qq2*256;
      int row = idx4 >> 4, col = (idx4 & 15) << 2;
      *(float4*)&sKx[row][col] = *(const float4*)&Km[(jbase+row)*64+col];
      *(float4*)&sVx[row][col] = *(const float4*)&Vm[(jbase+row)*64+col];
    }
    if (t < TILE) {
      int j = jbase + t;
      sPt[t][0]=pts[j*3+0]*PSCALE; sPt[t][1]=pts[j*3+1]*PSCALE; sPt[t][2]=pts[j*3+2]*PSCALE;
      sNj[t][0]=nuv[j*9+0]; sNj[t][1]=nuv[j*9+1]; sNj[t][2]=nuv[j*9+2];
    }
    __syncthreads();

    float F1[2][8], Wv[2];
    #pragma unroll
    for (int jj=0;jj<2;jj++) {
      int jloc = jl + (jj<<4);
      float dx = sPt[jloc][0]-pix, dy = sPt[jloc][1]-piy, dz = sPt[jloc][2]-piz;
      float ndot = nix*sNj[jloc][0] + niy*sNj[jloc][1] + niz*sNj[jloc][2];
      float d2r = dx*dx + dy*dy + dz*dz;
      float wf = 2.f - ndot;
      float d2 = d2r*wf*wf;
      float tp = fmaf(d2, 0.3333333333333333f, 1.f);
      Wv[jj] = __builtin_amdgcn_rcpf(tp*tp*tp);     // (1+d2/3)^-3
      float dd = __builtin_amdgcn_sqrtf(d2);
      float R[8];
      #pragma unroll
      for (int k=0;k<8;k++){ float u = dd - cen[k]; R[k] = __builtin_amdgcn_exp2f(u*u*mexp); }
      #pragma unroll
      for (int cc=0;cc<8;cc++) {
        float4 wx = *(const float4*)&sWX[r][cc*4];
        float p = b1pg[cc] + wx.x*dx + wx.y*dy + wx.z*dz + wx.w*ndot;
        #pragma unroll
        for (int k=0;k<8;k++) p = fmaf(R[k], wrg[cc*8+k], p);
        F1[jj][cc] = fmaxf(p, 0.f);
      }
    }

    #pragma unroll
    for (int h=0;h<8;h++) {
      float4 q0 = *(const float4*)&sQ[r][h*8];
      float4 q1 = *(const float4*)&sQ[r][h*8+4];
      float ew[2];
      float va[2][8];
      #pragma unroll
      for (int jj=0;jj<2;jj++) {
        int jloc = jl + (jj<<4);
        float4 k0 = *(const float4*)&sKx[jloc][h*8];
        float4 k1 = *(const float4*)&sKx[jloc][h*8+4];
        float S = d4(q0,k0) + d4(q1,k1);       // already in exp2 domain
        float e = __builtin_amdgcn_exp2f(S);
        lh[h] += e;
        ew[jj] = e * Wv[jj];
        float4 v0 = *(const float4*)&sVx[jloc][h*8];
        float4 v1 = *(const float4*)&sVx[jloc][h*8+4];
        va[jj][0]=v0.x; va[jj][1]=v0.y; va[jj][2]=v0.z; va[jj][3]=v0.w;
        va[jj][4]=v1.x; va[jj][5]=v1.y; va[jj][6]=v1.z; va[jj][7]=v1.w;
      }
      #pragma unroll
      for (int cc=0;cc<8;cc++) {
        float b2v = b2g[h*8+cc];
        float w2v[8];
        #pragma unroll
        for (int b=0;b<8;b++) w2v[b] = w2g[(h*8+cc)*8+b];
        #pragma unroll
        for (int jj=0;jj<2;jj++) {
          float fh = b2v;
          #pragma unroll
          for (int b=0;b<8;b++) fh = fmaf(F1[jj][b], w2v[b], fh);
          fh = fmaxf(fh, 0.f);
          acc[h*8+cc] = fmaf(ew[jj]*fh, va[jj][cc], acc[h*8+cc]);
        }
      }
    }
  }

  // reduce over the 16 j-lanes sharing a row: shfl within wave, LDS across waves
  #pragma unroll
  for (int o=0;o<64;o++){ acc[o] += __shfl_xor(acc[o],16); acc[o] += __shfl_xor(acc[o],32); }
  #pragma unroll
  for (int h=0;h<8;h++){ lh[h] += __shfl_xor(lh[h],16); lh[h] += __shfl_xor(lh[h],32); }
  __syncthreads();
  int wv = t >> 6, lane = t & 63;
  if (lane < 16) {
    #pragma unroll
    for (int o=0;o<64;o++) sRed[wv][lane][o] = acc[o];
    #pragma unroll
    for (int h=0;h<8;h++) sRed[wv][lane][64+h] = lh[h];
  }
  __syncthreads();
  for (int v2 = t; v2 < 16*72; v2 += 256) {
    int rr = v2/72, o = v2 - rr*72;
    float s = sRed[0][rr][o]+sRed[1][rr][o]+sRed[2][rr][o]+sRed[3][rr][o];
    part[(jc*NPTS + I0 + rr)*72 + o] = s;
  }
}

// ---------------- K4: merge chunk partials, divide by softmax denom, o1/o2 MLP, out group stats ----------------
__global__ __launch_bounds__(256) void k_agg(
  const float* __restrict__ part, const float* __restrict__ w_o1, const float* __restrict__ b_o1,
  const float* __restrict__ w_o2, const float* __restrict__ b_o2,
  float* __restrict__ o2b, float* __restrict__ stats)
{
  __shared__ float sh[4][64];
  __shared__ float sred[4][8];
  int t = threadIdx.x, w = t>>6, c = t&63;
  int i = blockIdx.x*4 + w;
  int h = c>>3;
  float a = 0.f, L = 0.f;
  #pragma unroll 1
  for (int jc=0;jc<NCHUNK;jc++){
    const float* p = part + (jc*NPTS + i)*72;
    a += p[c]; L += p[64+h];
  }
  float agg = a / L;
  sh[w][c] = agg; __syncthreads();
  float o1 = b_o1[c];
  #pragma unroll
  for (int k4=0;k4<16;k4++){
    float4 hv = *(const float4*)&sh[w][k4*4];
    o1 += d4(hv, *(const float4*)&w_o1[c*64+k4*4]);
  }
  o1 = leaky(o1);
  __syncthreads();
  sh[w][c] = o1; __syncthreads();
  float o2 = b_o2[c];
  #pragma unroll
  for (int k4=0;k4<16;k4++){
    float4 hv = *(const float4*)&sh[w][k4*4];
    o2 += d4(hv, *(const float4*)&w_o2[c*64+k4*4]);
  }
  o2 = leaky(o2);
  o2b[i*64+c] = o2;

  float s = o2, qq = o2*o2;
  s += __shfl_xor(s,1);  qq += __shfl_xor(qq,1);
  s += __shfl_xor(s,2);  qq += __shfl_xor(qq,2);
  s += __shfl_xor(s,4);  qq += __shfl_xor(qq,4);
  s += __shfl_xor(s,8);  qq += __shfl_xor(qq,8);
  if ((c&15)==0){ int g=c>>4; sred[w][g]=s; sred[w][4+g]=qq; }
  __syncthreads();
  if (t<8){ float v2 = sred[0][t]+sred[1][t]+sred[2][t]+sred[3][t]; atomicAdd(&stats[8+t], v2); }
}

// ---------------- K5: final group-norm + residual ----------------
__global__ __launch_bounds__(256) void k_out(
  const float* __restrict__ o2b, const float* __restrict__ stats,
  const float* __restrict__ g_out, const float* __restrict__ be_out,
  const float* __restrict__ feat, const float* __restrict__ w_res, const float* __restrict__ b_res,
  float* __restrict__ out)
{
  int t = threadIdx.x, w = t>>6, c = t&63;
  int i = blockIdx.x*4 + w;
  int g = c>>4;
  const float inv = 1.f/25600.f;
  float mu = stats[8+g]*inv;
  float var = stats[12+g]*inv - mu*mu;
  float rs = rsqrtf(var + 1e-5f);
  float on = (o2b[i*64+c]-mu)*rs*g_out[c] + be_out[c];
  const float4* f4 = (const float4*)(feat + i*16);
  const float4* wr = (const float4*)(w_res + c*16);
  float res = b_res[c] + d4(f4[0],wr[0]) + d4(f4[1],wr[1]) + d4(f4[2],wr[2]) + d4(f4[3],wr[3]);
  out[i*64+c] = on + res;
}

extern "C" void kernel_launch(void* const* d_in, const int* in_sizes, int n_in,
                              void* d_out, int out_size, void* d_ws, size_t ws_size,
                              hipStream_t stream) {
  const float* points  = (const float*)d_in[0];
  const float* nuv     = (const float*)d_in[1];
  const float* feat    = (const float*)d_in[2];
  const float* w_in1   = (const float*)d_in[3];
  const float* b_in1   = (const float*)d_in[4];
  const float* w_in2   = (const float*)d_in[5];
  const float* b_in2   = (const float*)d_in[6];
  const float* g_in    = (const float*)d_in[7];
  const float* be_in   = (const float*)d_in[8];
  const float* wq      = (const float*)d_in[9];
  const float* bq      = (const float*)d_in[10];
  const float* wk      = (const float*)d_in[11];
  const float* bk      = (const float*)d_in[12];
  const float* wv      = (const float*)d_in[13];
  const float* bv      = (const float*)d_in[14];
  const float* conv_w1 = (const float*)d_in[15];
  const float* conv_b1 = (const float*)d_in[16];
  const float* conv_w2 = (const float*)d_in[17];
  const float* conv_b2 = (const float*)d_in[18];
  const float* rbf_ls  = (const float*)d_in[19];
  const float* rbf_a   = (const float*)d_in[20];
  const float* rbf_b   = (const float*)d_in[21];
  const float* rbf_c   = (const float*)d_in[22];
  const float* w_o1    = (const float*)d_in[23];
  const float* b_o1    = (const float*)d_in[24];
  const float* w_o2    = (const float*)d_in[25];
  const float* b_o2    = (const float*)d_in[26];
  const float* g_out   = (const float*)d_in[27];
  const float* be_out  = (const float*)d_in[28];
  const float* w_res   = (const float*)d_in[29];
  const float* b_res   = (const float*)d_in[30];

  float* ws    = (float*)d_ws;
  float* h2    = ws;                 // 102400
  float* Q     = ws + 102400;        // 102400
  float* Km    = ws + 204800;        // 102400
  float* V     = ws + 307200;        // 102400
  float* stats = ws + 409600;        // 16
  float* wrg   = ws + 409616;        // 64
  float* b1pg  = ws + 409680;        // 8
  float* part  = ws + 409688;        // 10*1600*72 = 1152000
  float* o2b   = ws + 1561688;       // 102400
  float* out   = (float*)d_out;

  hipMemsetAsync(stats, 0, 16*sizeof(float), stream);
  k_in<<<400, 256, 0, stream>>>(feat, w_in1, b_in1, w_in2, b_in2,
                                conv_w1, conv_b1, rbf_a, rbf_b,
                                h2, stats, wrg, b1pg);
  k_qkv<<<400, 256, 0, stream>>>(h2, stats, g_in, be_in, wq, bq, wk, bk, wv, bv, Q, Km, V);
  k_pair<<<1000, 256, 0, stream>>>(Q, Km, V, points, nuv, conv_w1, wrg, b1pg,
                                   conv_w2, conv_b2, rbf_ls, rbf_c, part);
  k_agg<<<400, 256, 0, stream>>>(part, w_o1, b_o1, w_o2, b_o2, o2b, stats);
  k_out<<<400, 256, 0, stream>>>(o2b, stats, g_out, be_out, feat, w_res, b_res, out);
}